// Round 1
// baseline (478.245 us; speedup 1.0000x reference)
//
#include <hip/hip_runtime.h>
#include <hip/hip_bf16.h>
#include <stdint.h>

typedef __attribute__((ext_vector_type(8))) short short8;
typedef __attribute__((ext_vector_type(4))) float f32x4;

static __device__ __forceinline__ void gload_lds16(const void* g, void* l) {
  __builtin_amdgcn_global_load_lds((const __attribute__((address_space(1))) void*)g,
                                   (__attribute__((address_space(3))) void*)l,
                                   16, 0, 0);
}

static __device__ __forceinline__ unsigned short f2bf(float f) {
  union { __hip_bfloat16 h; unsigned short s; } u;
  u.h = __float2bfloat16(f);
  return u.s;
}

__global__ void cast_f32_bf16(const float* __restrict__ src,
                              unsigned short* __restrict__ dst, int n4) {
  int i = blockIdx.x * 256 + threadIdx.x;
  if (i >= n4) return;
  float4 v = reinterpret_cast<const float4*>(src)[i];
  ushort4 o;
  o.x = f2bf(v.x); o.y = f2bf(v.y); o.z = f2bf(v.z); o.w = f2bf(v.w);
  reinterpret_cast<ushort4*>(dst)[i] = o;
}

// C[M][N] = A[M][K] @ B[N][K]^T. A,B bf16 (as ushort bits), OutT = ushort(bf16) or float.
// m97 structure: 128x128 tile, BK=32, 4 waves each owning a 64x64 quadrant,
// global_load_lds width-16 staging, 16x16x32 bf16 MFMA, f32 accum.
template <typename OutT>
__global__ __launch_bounds__(256) void gemm_nt(const unsigned short* __restrict__ A,
                                               const unsigned short* __restrict__ B,
                                               OutT* __restrict__ C,
                                               int M, int N, int K) {
  __shared__ short sA[128 * 32];
  __shared__ short sB[128 * 32];
  const int t = threadIdx.x;
  const int w = t >> 6, l = t & 63, lg = l >> 4, lr = l & 15;
  const int wr = w >> 1, wc = w & 1;
  const int brow = blockIdx.y << 7, bcol = blockIdx.x << 7;

  f32x4 acc[4][4] = {};

  for (int kt = 0; kt < K; kt += 32) {
    __syncthreads();  // previous iter's LDS reads done before overwrite
#pragma unroll
    for (int r = 0; r < 2; ++r) {
      const int byteoff = t * 16 + r * 4096;     // 8 KB per tile, 2 rounds
      const int row = byteoff >> 6, inrow = byteoff & 63;  // 64 B per row (32 bf16)
      gload_lds16((const char*)A + ((size_t)(brow + row) * K + kt) * 2 + inrow,
                  (char*)sA + byteoff);
      gload_lds16((const char*)B + ((size_t)(bcol + row) * K + kt) * 2 + inrow,
                  (char*)sB + byteoff);
    }
    __syncthreads();  // compiler emits vmcnt(0) drain before s_barrier

    short8 af[4], bfr[4];
#pragma unroll
    for (int m = 0; m < 4; ++m)
      af[m] = *reinterpret_cast<const short8*>(sA + (wr * 64 + m * 16 + lr) * 32 + lg * 8);
#pragma unroll
    for (int n = 0; n < 4; ++n)
      bfr[n] = *reinterpret_cast<const short8*>(sB + (wc * 64 + n * 16 + lr) * 32 + lg * 8);
#pragma unroll
    for (int m = 0; m < 4; ++m)
#pragma unroll
      for (int n = 0; n < 4; ++n)
        acc[m][n] = __builtin_amdgcn_mfma_f32_16x16x32_bf16(af[m], bfr[n], acc[m][n], 0, 0, 0);
  }

  // C/D layout: col = lane&15, row = (lane>>4)*4 + reg  [m89 verified]
#pragma unroll
  for (int m = 0; m < 4; ++m) {
#pragma unroll
    for (int n = 0; n < 4; ++n) {
#pragma unroll
      for (int j = 0; j < 4; ++j) {
        const int rr = brow + wr * 64 + m * 16 + lg * 4 + j;
        const int cc = bcol + wc * 64 + n * 16 + lr;
        if constexpr (sizeof(OutT) == 2) {
          C[(size_t)rr * N + cc] = (OutT)f2bf(acc[m][n][j]);
        } else {
          C[(size_t)rr * N + cc] = acc[m][n][j];
        }
      }
    }
  }
}

// Causal flash attention.
// Q, K: [B*S, D] bf16 rows (head h uses cols h*64..h*64+63).
// Vt:   [D, B*S] bf16 (V transposed) so PV B-fragments are kv-contiguous.
// Block: 4 waves, 64 q-rows (16 per wave), KV tiles of 64. grid = (S/64, B*H).
__global__ __launch_bounds__(256) void attn_kernel(const unsigned short* __restrict__ Qg,
                                                   const unsigned short* __restrict__ Kg,
                                                   const unsigned short* __restrict__ Vtg,
                                                   unsigned short* __restrict__ AO) {
  const int S = 2048, D = 1024, SN = 8192;  // SN = B*S
  const int qt = blockIdx.x;
  const int bh = blockIdx.y;
  const int b = bh >> 4, h = bh & 15;
  const int t = threadIdx.x;
  const int w = t >> 6, l = t & 63, lg = l >> 4, lr = l & 15;

  __shared__ short sK[64 * 64];     // [kv][dk], XOR-swizzled rows (128 B/row)
  __shared__ short sV[64 * 64];     // [dk][kv] (=V^T), XOR-swizzled
  __shared__ short sP[4 * 16 * 64]; // per-wave P[q=16][kv=64], XOR-swizzled

  // Hoist Q fragments: lane lr -> q-row, 8 contiguous dk elems per (kk,lg).
  short8 qf[2];
  {
    const unsigned short* qbase = Qg + (size_t)(b * S + qt * 64 + w * 16 + lr) * D + h * 64;
    qf[0] = *reinterpret_cast<const short8*>(qbase + lg * 8);
    qf[1] = *reinterpret_cast<const short8*>(qbase + 32 + lg * 8);
  }

  f32x4 o[4] = {};
  float mrow[4], lrow[4];
#pragma unroll
  for (int r = 0; r < 4; ++r) { mrow[r] = -INFINITY; lrow[r] = 0.f; }

  const int nkv = qt + 1;  // causal: only tiles with kv0 <= qt*64
  for (int kvt = 0; kvt < nkv; ++kvt) {
    const int kv0 = kvt * 64;
    __syncthreads();  // PV of previous tile done before restage
#pragma unroll
    for (int r = 0; r < 2; ++r) {
      const int byteoff = t * 16 + r * 4096;
      const int row = byteoff >> 7;          // 128 B per row
      const int inrow = byteoff & 127;
      const int lin = inrow ^ ((row & 7) << 4);  // inverse-swizzled global source
      gload_lds16((const char*)Kg + ((size_t)(b * S + kv0 + row) * D + h * 64) * 2 + lin,
                  (char*)sK + byteoff);
      gload_lds16((const char*)Vtg + ((size_t)(h * 64 + row) * SN + b * S + kv0) * 2 + lin,
                  (char*)sV + byteoff);
    }
    __syncthreads();

    // S = Q K^T  (rows q in 16-lane-group/reg space, cols kv in lane space)
    f32x4 sc[4] = {};
#pragma unroll
    for (int n = 0; n < 4; ++n) {
#pragma unroll
      for (int kk = 0; kk < 2; ++kk) {
        const int row = n * 16 + lr;
        const short8 kf = *reinterpret_cast<const short8*>(
            (const char*)sK + (row << 7) + ((kk * 64 + lg * 16) ^ ((row & 7) << 4)));
        sc[n] = __builtin_amdgcn_mfma_f32_16x16x32_bf16(qf[kk], kf, sc[n], 0, 0, 0);
      }
    }

    // scale + causal mask (only the diagonal tile needs masking)
    float p[4][4];
    const bool diag = (kvt == qt);
#pragma unroll
    for (int n = 0; n < 4; ++n) {
#pragma unroll
      for (int r = 0; r < 4; ++r) {
        float v = sc[n][r] * 0.125f;  // 1/sqrt(64)
        if (diag) {
          const int ql = w * 16 + lg * 4 + r;
          const int kl = n * 16 + lr;
          if (kl > ql) v = -INFINITY;
        }
        p[n][r] = v;
      }
    }

    // online softmax, row = (lg*4 + r), cols spread over 16 lanes x 4 n-tiles
    float mnew[4], alpha[4];
#pragma unroll
    for (int r = 0; r < 4; ++r) {
      float mx = fmaxf(fmaxf(p[0][r], p[1][r]), fmaxf(p[2][r], p[3][r]));
      mx = fmaxf(mx, __shfl_xor(mx, 1));
      mx = fmaxf(mx, __shfl_xor(mx, 2));
      mx = fmaxf(mx, __shfl_xor(mx, 4));
      mx = fmaxf(mx, __shfl_xor(mx, 8));
      mnew[r] = fmaxf(mrow[r], mx);
      alpha[r] = __expf(mrow[r] - mnew[r]);
      mrow[r] = mnew[r];
    }
#pragma unroll
    for (int r = 0; r < 4; ++r) {
      float s0 = 0.f;
#pragma unroll
      for (int n = 0; n < 4; ++n) {
        const float e = __expf(p[n][r] - mnew[r]);
        p[n][r] = e;
        s0 += e;
      }
      s0 += __shfl_xor(s0, 1);
      s0 += __shfl_xor(s0, 2);
      s0 += __shfl_xor(s0, 4);
      s0 += __shfl_xor(s0, 8);
      lrow[r] = lrow[r] * alpha[r] + s0;
#pragma unroll
      for (int dn = 0; dn < 4; ++dn) o[dn][r] *= alpha[r];
    }

    // P -> wave-private LDS (bf16, swizzled) to reach MFMA A-fragment layout
#pragma unroll
    for (int r = 0; r < 4; ++r) {
      const int row = lg * 4 + r;
#pragma unroll
      for (int n = 0; n < 4; ++n) {
        const int lbyte = (n * 16 + lr) << 1;
        short* wp = (short*)((char*)sP + (w << 11) + (row << 7) +
                             (lbyte ^ ((row & 7) << 4)));
        *wp = (short)f2bf(p[n][r]);
      }
    }
    __syncthreads();  // make sP writes visible (and order vs PV reads)

    // O += P @ V  (A-frags from sP rows=q, B-frags from sV rows=d)
#pragma unroll
    for (int kk = 0; kk < 2; ++kk) {
      const short8 pa = *reinterpret_cast<const short8*>(
          (const char*)sP + (w << 11) + (lr << 7) +
          ((kk * 64 + lg * 16) ^ ((lr & 7) << 4)));
#pragma unroll
      for (int dn = 0; dn < 4; ++dn) {
        const int vrow = dn * 16 + lr;
        const short8 vb = *reinterpret_cast<const short8*>(
            (const char*)sV + (vrow << 7) + ((kk * 64 + lg * 16) ^ ((vrow & 7) << 4)));
        o[dn] = __builtin_amdgcn_mfma_f32_16x16x32_bf16(pa, vb, o[dn], 0, 0, 0);
      }
    }
  }

  // epilogue: normalize by l and store bf16
#pragma unroll
  for (int r = 0; r < 4; ++r) {
    const float inv = 1.f / lrow[r];
    const size_t orow = (size_t)(b * S + qt * 64 + w * 16 + lg * 4 + r) * D + h * 64;
#pragma unroll
    for (int dn = 0; dn < 4; ++dn) {
      AO[orow + dn * 16 + lr] = f2bf(o[dn][r] * inv);
    }
  }
}

extern "C" void kernel_launch(void* const* d_in, const int* in_sizes, int n_in,
                              void* d_out, int out_size, void* d_ws, size_t ws_size,
                              hipStream_t stream) {
  const float* x  = (const float*)d_in[0];
  const float* Wq = (const float*)d_in[1];
  const float* Wk = (const float*)d_in[2];
  const float* Wv = (const float*)d_in[3];
  const float* Wo = (const float*)d_in[4];
  float* out = (float*)d_out;

  // ws layout (bytes): all bf16 scratch
  char* ws = (char*)d_ws;
  unsigned short* xb  = (unsigned short*)(ws);               // 8192x1024 (16 MB)
  unsigned short* Wqb = (unsigned short*)(ws + 16777216);    // 1024x1024 (2 MB)
  unsigned short* Wkb = (unsigned short*)(ws + 18874368);
  unsigned short* Wvb = (unsigned short*)(ws + 20971520);
  unsigned short* Wob = (unsigned short*)(ws + 23068672);
  unsigned short* Qb  = (unsigned short*)(ws + 25165824);    // 8192x1024
  unsigned short* Kb  = (unsigned short*)(ws + 41943040);    // 8192x1024
  unsigned short* Vt  = (unsigned short*)(ws + 58720256);    // 1024x8192 (V^T)
  unsigned short* AO  = (unsigned short*)(ws + 75497472);    // 8192x1024

  cast_f32_bf16<<<8192, 256, 0, stream>>>(x,  xb,  2097152);
  cast_f32_bf16<<<1024, 256, 0, stream>>>(Wq, Wqb, 262144);
  cast_f32_bf16<<<1024, 256, 0, stream>>>(Wk, Wkb, 262144);
  cast_f32_bf16<<<1024, 256, 0, stream>>>(Wv, Wvb, 262144);
  cast_f32_bf16<<<1024, 256, 0, stream>>>(Wo, Wob, 262144);

  const dim3 blk(256);
  // Q = x Wq^T, K = x Wk^T : [8192,1024]
  gemm_nt<unsigned short><<<dim3(8, 64), blk, 0, stream>>>(xb, Wqb, Qb, 8192, 1024, 1024);
  gemm_nt<unsigned short><<<dim3(8, 64), blk, 0, stream>>>(xb, Wkb, Kb, 8192, 1024, 1024);
  // Vt = Wv x^T : [1024, 8192]  (V transposed for attention PV)
  gemm_nt<unsigned short><<<dim3(64, 8), blk, 0, stream>>>(Wvb, xb, Vt, 1024, 8192, 1024);

  attn_kernel<<<dim3(32, 64), blk, 0, stream>>>(Qb, Kb, Vt, AO);

  // out = AO Wo^T, f32 output
  gemm_nt<float><<<dim3(8, 64), blk, 0, stream>>>(AO, Wob, out, 8192, 1024, 1024);
}

// Round 2
// 430.319 us; speedup vs baseline: 1.1114x; 1.1114x over previous
//
#include <hip/hip_runtime.h>
#include <hip/hip_bf16.h>
#include <stdint.h>

typedef __attribute__((ext_vector_type(8))) short short8;
typedef __attribute__((ext_vector_type(4))) float f32x4;

static __device__ __forceinline__ void gload_lds16(const void* g, void* l) {
  __builtin_amdgcn_global_load_lds((const __attribute__((address_space(1))) void*)g,
                                   (__attribute__((address_space(3))) void*)l,
                                   16, 0, 0);
}

static __device__ __forceinline__ unsigned short f2bf(float f) {
  union { __hip_bfloat16 h; unsigned short s; } u;
  u.h = __float2bfloat16(f);
  return u.s;
}

__global__ void cast_f32_bf16(const float* __restrict__ src,
                              unsigned short* __restrict__ dst, int n4) {
  int i = blockIdx.x * 256 + threadIdx.x;
  if (i >= n4) return;
  float4 v = reinterpret_cast<const float4*>(src)[i];
  ushort4 o;
  o.x = f2bf(v.x); o.y = f2bf(v.y); o.z = f2bf(v.z); o.w = f2bf(v.w);
  reinterpret_cast<ushort4*>(dst)[i] = o;
}

// C[M][N] = A[M][K] @ B[N][K]^T. A,B bf16 (as ushort bits), OutT = ushort(bf16) or float.
// m97 structure: 128x128 tile, BK=32, 4 waves each owning a 64x64 quadrant,
// global_load_lds width-16 staging, 16x16x32 bf16 MFMA, f32 accum.
template <typename OutT>
__global__ __launch_bounds__(256) void gemm_nt(const unsigned short* __restrict__ A,
                                               const unsigned short* __restrict__ B,
                                               OutT* __restrict__ C,
                                               int M, int N, int K) {
  __shared__ short sA[128 * 32];
  __shared__ short sB[128 * 32];
  const int t = threadIdx.x;
  const int w = t >> 6, l = t & 63, lg = l >> 4, lr = l & 15;
  const int wr = w >> 1, wc = w & 1;
  const int brow = blockIdx.y << 7, bcol = blockIdx.x << 7;

  f32x4 acc[4][4] = {};

  for (int kt = 0; kt < K; kt += 32) {
    __syncthreads();  // previous iter's LDS reads done before overwrite
#pragma unroll
    for (int r = 0; r < 2; ++r) {
      const int byteoff = t * 16 + r * 4096;     // 8 KB per tile, 2 rounds
      const int row = byteoff >> 6, inrow = byteoff & 63;  // 64 B per row (32 bf16)
      gload_lds16((const char*)A + ((size_t)(brow + row) * K + kt) * 2 + inrow,
                  (char*)sA + byteoff);
      gload_lds16((const char*)B + ((size_t)(bcol + row) * K + kt) * 2 + inrow,
                  (char*)sB + byteoff);
    }
    __syncthreads();  // compiler emits vmcnt(0) drain before s_barrier

    short8 af[4], bfr[4];
#pragma unroll
    for (int m = 0; m < 4; ++m)
      af[m] = *reinterpret_cast<const short8*>(sA + (wr * 64 + m * 16 + lr) * 32 + lg * 8);
#pragma unroll
    for (int n = 0; n < 4; ++n)
      bfr[n] = *reinterpret_cast<const short8*>(sB + (wc * 64 + n * 16 + lr) * 32 + lg * 8);
#pragma unroll
    for (int m = 0; m < 4; ++m)
#pragma unroll
      for (int n = 0; n < 4; ++n)
        acc[m][n] = __builtin_amdgcn_mfma_f32_16x16x32_bf16(af[m], bfr[n], acc[m][n], 0, 0, 0);
  }

  // C/D layout: col = lane&15, row = (lane>>4)*4 + reg  [m89 verified]
#pragma unroll
  for (int m = 0; m < 4; ++m) {
#pragma unroll
    for (int n = 0; n < 4; ++n) {
#pragma unroll
      for (int j = 0; j < 4; ++j) {
        const int rr = brow + wr * 64 + m * 16 + lg * 4 + j;
        const int cc = bcol + wc * 64 + n * 16 + lr;
        if constexpr (sizeof(OutT) == 2) {
          C[(size_t)rr * N + cc] = (OutT)f2bf(acc[m][n][j]);
        } else {
          C[(size_t)rr * N + cc] = acc[m][n][j];
        }
      }
    }
  }
}

// Causal flash attention, double-buffered K/V staging (T3 2-phase template).
// Q, K: [B*S, D] bf16 rows (head h uses cols h*64..h*64+63).
// Vt:   [D, B*S] bf16 (V transposed) so PV B-fragments are kv-contiguous.
// Block: 4 waves, 64 q-rows (16 per wave), KV tiles of 64. grid = (S/64, B*H).
// One __syncthreads per KV tile; sP is wave-private (no barrier needed).
__global__ __launch_bounds__(256) void attn_kernel(const unsigned short* __restrict__ Qg,
                                                   const unsigned short* __restrict__ Kg,
                                                   const unsigned short* __restrict__ Vtg,
                                                   unsigned short* __restrict__ AO) {
  const int S = 2048, D = 1024, SN = 8192;  // SN = B*S
  const int qt = blockIdx.x;
  const int bh = blockIdx.y;
  const int b = bh >> 4, h = bh & 15;
  const int t = threadIdx.x;
  const int w = t >> 6, l = t & 63, lg = l >> 4, lr = l & 15;

  __shared__ short sK[2][64 * 64];  // [kv][dk], XOR-swizzled rows (128 B/row)
  __shared__ short sV[2][64 * 64];  // [dk][kv] (=V^T), XOR-swizzled
  __shared__ short sP[4 * 16 * 64]; // per-wave P[q=16][kv=64], XOR-swizzled

  // Staging geometry: per-thread constants (r = 0,1 rounds of 4 KB).
  int sboff[2], slin[2], srow[2];
#pragma unroll
  for (int r = 0; r < 2; ++r) {
    sboff[r] = t * 16 + r * 4096;
    srow[r] = sboff[r] >> 7;                       // 128 B per row
    const int inrow = sboff[r] & 127;
    slin[r] = inrow ^ ((srow[r] & 7) << 4);        // inverse-swizzled global source
  }
  const char* Kbase = (const char*)Kg + ((size_t)(b * S) * D + h * 64) * 2;
  const char* Vbase = (const char*)Vtg + ((size_t)(h * 64) * SN + (size_t)b * S) * 2;

  // Hoist Q fragments: lane lr -> q-row, 8 contiguous dk elems per (kk,lg).
  short8 qf[2];
  {
    const unsigned short* qbase = Qg + (size_t)(b * S + qt * 64 + w * 16 + lr) * D + h * 64;
    qf[0] = *reinterpret_cast<const short8*>(qbase + lg * 8);
    qf[1] = *reinterpret_cast<const short8*>(qbase + 32 + lg * 8);
  }

  f32x4 o[4] = {};
  float mrow[4], lrow[4];
#pragma unroll
  for (int r = 0; r < 4; ++r) { mrow[r] = -INFINITY; lrow[r] = 0.f; }

  const float SCL = 0.125f * 1.44269504089f;  // 1/sqrt(dk) * log2(e): exp2-domain softmax

  const int nkv = qt + 1;  // causal: only tiles with kv0 <= qt*64

  // prologue: stage tile 0 into buf 0
#pragma unroll
  for (int r = 0; r < 2; ++r) {
    gload_lds16(Kbase + (size_t)srow[r] * 2048 + slin[r], (char*)sK[0] + sboff[r]);
    gload_lds16(Vbase + (size_t)srow[r] * 16384 + slin[r], (char*)sV[0] + sboff[r]);
  }
  __syncthreads();  // vmcnt(0) drain: buf0 ready

  int cur = 0;
  for (int kvt = 0; kvt < nkv; ++kvt) {
    // issue next tile's staging into buf^1 (latency hidden under compute below)
    if (kvt + 1 < nkv) {
      const size_t kv0n = (size_t)(kvt + 1) * 64;
#pragma unroll
      for (int r = 0; r < 2; ++r) {
        gload_lds16(Kbase + (kv0n + srow[r]) * 2048 + slin[r],
                    (char*)sK[cur ^ 1] + sboff[r]);
        gload_lds16(Vbase + (size_t)srow[r] * 16384 + kv0n * 2 + slin[r],
                    (char*)sV[cur ^ 1] + sboff[r]);
      }
    }

    const char* sKc = (const char*)sK[cur];
    const char* sVc = (const char*)sV[cur];

    // S = Q K^T  (rows q in 16-lane-group/reg space, cols kv in lane space)
    f32x4 sc[4] = {};
#pragma unroll
    for (int n = 0; n < 4; ++n) {
#pragma unroll
      for (int kk = 0; kk < 2; ++kk) {
        const int row = n * 16 + lr;
        const short8 kf = *reinterpret_cast<const short8*>(
            sKc + (row << 7) + ((kk * 64 + lg * 16) ^ ((row & 7) << 4)));
        sc[n] = __builtin_amdgcn_mfma_f32_16x16x32_bf16(qf[kk], kf, sc[n], 0, 0, 0);
      }
    }

    // scale (exp2 domain) + causal mask (only the diagonal tile needs masking)
    float p[4][4];
    const bool diag = (kvt == qt);
#pragma unroll
    for (int n = 0; n < 4; ++n) {
#pragma unroll
      for (int r = 0; r < 4; ++r) {
        float v = sc[n][r] * SCL;
        if (diag) {
          const int ql = w * 16 + lg * 4 + r;
          const int kl = n * 16 + lr;
          if (kl > ql) v = -INFINITY;
        }
        p[n][r] = v;
      }
    }

    // online softmax (exp2 domain), row = (lg*4 + r), cols over 16 lanes x 4 n-tiles
    float mnew[4], alpha[4];
#pragma unroll
    for (int r = 0; r < 4; ++r) {
      float mx = fmaxf(fmaxf(p[0][r], p[1][r]), fmaxf(p[2][r], p[3][r]));
      mx = fmaxf(mx, __shfl_xor(mx, 1));
      mx = fmaxf(mx, __shfl_xor(mx, 2));
      mx = fmaxf(mx, __shfl_xor(mx, 4));
      mx = fmaxf(mx, __shfl_xor(mx, 8));
      mnew[r] = fmaxf(mrow[r], mx);
      alpha[r] = __builtin_amdgcn_exp2f(mrow[r] - mnew[r]);
      mrow[r] = mnew[r];
    }
#pragma unroll
    for (int r = 0; r < 4; ++r) {
      float s0 = 0.f;
#pragma unroll
      for (int n = 0; n < 4; ++n) {
        const float e = __builtin_amdgcn_exp2f(p[n][r] - mnew[r]);
        p[n][r] = e;
        s0 += e;
      }
      s0 += __shfl_xor(s0, 1);
      s0 += __shfl_xor(s0, 2);
      s0 += __shfl_xor(s0, 4);
      s0 += __shfl_xor(s0, 8);
      lrow[r] = lrow[r] * alpha[r] + s0;
#pragma unroll
      for (int dn = 0; dn < 4; ++dn) o[dn][r] *= alpha[r];
    }

    // P -> wave-private LDS (bf16, swizzled) to reach MFMA A-fragment layout.
    // No barrier: same-wave ds_write -> ds_read ordering via compiler lgkmcnt.
#pragma unroll
    for (int r = 0; r < 4; ++r) {
      const int row = lg * 4 + r;
#pragma unroll
      for (int n = 0; n < 4; ++n) {
        const int lbyte = (n * 16 + lr) << 1;
        short* wp = (short*)((char*)sP + (w << 11) + (row << 7) +
                             (lbyte ^ ((row & 7) << 4)));
        *wp = (short)f2bf(p[n][r]);
      }
    }

    // O += P @ V  (A-frags from sP rows=q, B-frags from sV rows=d)
#pragma unroll
    for (int kk = 0; kk < 2; ++kk) {
      const short8 pa = *reinterpret_cast<const short8*>(
          (const char*)sP + (w << 11) + (lr << 7) +
          ((kk * 64 + lg * 16) ^ ((lr & 7) << 4)));
#pragma unroll
      for (int dn = 0; dn < 4; ++dn) {
        const int vrow = dn * 16 + lr;
        const short8 vb = *reinterpret_cast<const short8*>(
            sVc + (vrow << 7) + ((kk * 64 + lg * 16) ^ ((vrow & 7) << 4)));
        o[dn] = __builtin_amdgcn_mfma_f32_16x16x32_bf16(pa, vb, o[dn], 0, 0, 0);
      }
    }

    __syncthreads();  // vmcnt(0): next buf staged; also guards buf reuse
    cur ^= 1;
  }

  // epilogue: normalize by l and store bf16
#pragma unroll
  for (int r = 0; r < 4; ++r) {
    const float inv = __builtin_amdgcn_rcpf(lrow[r]);
    const size_t orow = (size_t)(b * S + qt * 64 + w * 16 + lg * 4 + r) * D + h * 64;
#pragma unroll
    for (int dn = 0; dn < 4; ++dn) {
      AO[orow + dn * 16 + lr] = f2bf(o[dn][r] * inv);
    }
  }
}

extern "C" void kernel_launch(void* const* d_in, const int* in_sizes, int n_in,
                              void* d_out, int out_size, void* d_ws, size_t ws_size,
                              hipStream_t stream) {
  const float* x  = (const float*)d_in[0];
  const float* Wq = (const float*)d_in[1];
  const float* Wk = (const float*)d_in[2];
  const float* Wv = (const float*)d_in[3];
  const float* Wo = (const float*)d_in[4];
  float* out = (float*)d_out;

  // ws layout (bytes): all bf16 scratch
  char* ws = (char*)d_ws;
  unsigned short* xb  = (unsigned short*)(ws);               // 8192x1024 (16 MB)
  unsigned short* Wqb = (unsigned short*)(ws + 16777216);    // 1024x1024 (2 MB)
  unsigned short* Wkb = (unsigned short*)(ws + 18874368);
  unsigned short* Wvb = (unsigned short*)(ws + 20971520);
  unsigned short* Wob = (unsigned short*)(ws + 23068672);
  unsigned short* Qb  = (unsigned short*)(ws + 25165824);    // 8192x1024
  unsigned short* Kb  = (unsigned short*)(ws + 41943040);    // 8192x1024
  unsigned short* Vt  = (unsigned short*)(ws + 58720256);    // 1024x8192 (V^T)
  unsigned short* AO  = (unsigned short*)(ws + 75497472);    // 8192x1024

  cast_f32_bf16<<<8192, 256, 0, stream>>>(x,  xb,  2097152);
  cast_f32_bf16<<<1024, 256, 0, stream>>>(Wq, Wqb, 262144);
  cast_f32_bf16<<<1024, 256, 0, stream>>>(Wk, Wkb, 262144);
  cast_f32_bf16<<<1024, 256, 0, stream>>>(Wv, Wvb, 262144);
  cast_f32_bf16<<<1024, 256, 0, stream>>>(Wo, Wob, 262144);

  const dim3 blk(256);
  // Q = x Wq^T, K = x Wk^T : [8192,1024]
  gemm_nt<unsigned short><<<dim3(8, 64), blk, 0, stream>>>(xb, Wqb, Qb, 8192, 1024, 1024);
  gemm_nt<unsigned short><<<dim3(8, 64), blk, 0, stream>>>(xb, Wkb, Kb, 8192, 1024, 1024);
  // Vt = Wv x^T : [1024, 8192]  (V transposed for attention PV)
  gemm_nt<unsigned short><<<dim3(64, 8), blk, 0, stream>>>(Wvb, xb, Vt, 1024, 8192, 1024);

  attn_kernel<<<dim3(32, 64), blk, 0, stream>>>(Qb, Kb, Vt, AO);

  // out = AO Wo^T, f32 output
  gemm_nt<float><<<dim3(8, 64), blk, 0, stream>>>(AO, Wob, out, 8192, 1024, 1024);
}

// Round 3
// 288.691 us; speedup vs baseline: 1.6566x; 1.4906x over previous
//
#include <hip/hip_runtime.h>
#include <hip/hip_bf16.h>
#include <stdint.h>

typedef __attribute__((ext_vector_type(8))) short short8;
typedef __attribute__((ext_vector_type(4))) float f32x4;

static __device__ __forceinline__ void gload_lds16(const void* g, void* l) {
  __builtin_amdgcn_global_load_lds((const __attribute__((address_space(1))) void*)g,
                                   (__attribute__((address_space(3))) void*)l,
                                   16, 0, 0);
}

static __device__ __forceinline__ unsigned short f2bf(float f) {
  union { __hip_bfloat16 h; unsigned short s; } u;
  u.h = __float2bfloat16(f);
  return u.s;
}

__global__ void cast_f32_bf16(const float* __restrict__ src,
                              unsigned short* __restrict__ dst, int n4) {
  int i = blockIdx.x * 256 + threadIdx.x;
  if (i >= n4) return;
  float4 v = reinterpret_cast<const float4*>(src)[i];
  ushort4 o;
  o.x = f2bf(v.x); o.y = f2bf(v.y); o.z = f2bf(v.z); o.w = f2bf(v.w);
  reinterpret_cast<ushort4*>(dst)[i] = o;
}

// C[M][N] = A[M][K] @ B[N][K]^T. m97 structure + T3 minimum 2-phase:
// double-buffered LDS, stage(next) issued BEFORE compute(cur), one barrier/K-step.
template <typename OutT>
__global__ __launch_bounds__(256) void gemm_nt(const unsigned short* __restrict__ A,
                                               const unsigned short* __restrict__ B,
                                               OutT* __restrict__ C,
                                               int M, int N, int K) {
  __shared__ short sA[2][128 * 32];
  __shared__ short sB[2][128 * 32];
  const int t = threadIdx.x;
  const int w = t >> 6, l = t & 63, lg = l >> 4, lr = l & 15;
  const int wr = w >> 1, wc = w & 1;
  const int brow = blockIdx.y << 7, bcol = blockIdx.x << 7;

  f32x4 acc[4][4] = {};

  auto stage = [&](int buf, int kt) {
#pragma unroll
    for (int r = 0; r < 2; ++r) {
      const int byteoff = t * 16 + r * 4096;
      const int row = byteoff >> 6, inrow = byteoff & 63;  // 64 B per row (32 bf16)
      gload_lds16((const char*)A + ((size_t)(brow + row) * K + kt) * 2 + inrow,
                  (char*)sA[buf] + byteoff);
      gload_lds16((const char*)B + ((size_t)(bcol + row) * K + kt) * 2 + inrow,
                  (char*)sB[buf] + byteoff);
    }
  };

  const int nkt = K >> 5;
  stage(0, 0);
  __syncthreads();
  int cur = 0;

  for (int kti = 0; kti < nkt; ++kti) {
    if (kti + 1 < nkt) stage(cur ^ 1, (kti + 1) << 5);

    short8 af[4], bfr[4];
#pragma unroll
    for (int m = 0; m < 4; ++m)
      af[m] = *reinterpret_cast<const short8*>(sA[cur] + (wr * 64 + m * 16 + lr) * 32 + lg * 8);
#pragma unroll
    for (int n = 0; n < 4; ++n)
      bfr[n] = *reinterpret_cast<const short8*>(sB[cur] + (wc * 64 + n * 16 + lr) * 32 + lg * 8);
#pragma unroll
    for (int m = 0; m < 4; ++m)
#pragma unroll
      for (int n = 0; n < 4; ++n)
        acc[m][n] = __builtin_amdgcn_mfma_f32_16x16x32_bf16(af[m], bfr[n], acc[m][n], 0, 0, 0);

    __syncthreads();  // drains prefetch vmcnt; also guards buffer reuse
    cur ^= 1;
  }

  // C/D layout: col = lane&15, row = (lane>>4)*4 + reg  [m89 verified]
#pragma unroll
  for (int m = 0; m < 4; ++m) {
#pragma unroll
    for (int n = 0; n < 4; ++n) {
#pragma unroll
      for (int j = 0; j < 4; ++j) {
        const int rr = brow + wr * 64 + m * 16 + lg * 4 + j;
        const int cc = bcol + wc * 64 + n * 16 + lr;
        if constexpr (sizeof(OutT) == 2) {
          C[(size_t)rr * N + cc] = (OutT)f2bf(acc[m][n][j]);
        } else {
          C[(size_t)rr * N + cc] = acc[m][n][j];
        }
      }
    }
  }
}

// Causal flash attention, swapped-QK^T per-lane softmax, paired q-tiles.
// Q, K: [B*S, D] bf16 rows (head h uses cols h*64..h*64+63).
// Vt:   [D, B*S] bf16 (V transposed) so PV B-fragments are kv-contiguous.
// Block: 4 waves, one 64-row q-tile at a time; processes qt=qp then qt=31-qp
// (uniform 33 KV tiles per block). Grid: 1024 blocks, XCD-grouped so each
// XCD owns 8 consecutive (b,h) heads (K/V working set = 4 MB = one L2).
__global__ __launch_bounds__(256) void attn_kernel(const unsigned short* __restrict__ Qg,
                                                   const unsigned short* __restrict__ Kg,
                                                   const unsigned short* __restrict__ Vtg,
                                                   unsigned short* __restrict__ AO) {
  const int S = 2048, D = 1024, SN = 8192;  // SN = B*S
  const int i = blockIdx.x;
  const int lid = (i & 7) * 128 + (i >> 3);  // XCD k <- lids [128k,128k+128)
  const int qp = lid & 15;
  const int bh = lid >> 4;
  const int b = bh >> 4, h = bh & 15;
  const int t = threadIdx.x;
  const int w = t >> 6, l = t & 63, lg = l >> 4, lr = l & 15;

  __shared__ short sK[2][64 * 64];  // [kv][dk], XOR-swizzled rows (128 B/row)
  __shared__ short sV[2][64 * 64];  // [dk][kv] (=V^T), XOR-swizzled
  __shared__ short sP[4 * 16 * 64]; // per-wave P[q=16][kv=64], XOR-swizzled

  int sboff[2], slin[2], srow[2];
#pragma unroll
  for (int r = 0; r < 2; ++r) {
    sboff[r] = t * 16 + r * 4096;
    srow[r] = sboff[r] >> 7;                 // 128 B per row
    slin[r] = (sboff[r] & 127) ^ ((srow[r] & 7) << 4);  // inverse-swizzled source
  }
  const char* Kbase = (const char*)Kg + ((size_t)(b * S) * D + h * 64) * 2;
  const char* Vbase = (const char*)Vtg + ((size_t)(h * 64) * SN + (size_t)b * S) * 2;

  auto stage = [&](int buf, int kvt) {
    const size_t kv0 = (size_t)kvt * 64;
#pragma unroll
    for (int r = 0; r < 2; ++r) {
      gload_lds16(Kbase + (kv0 + srow[r]) * 2048 + slin[r], (char*)sK[buf] + sboff[r]);
      gload_lds16(Vbase + (size_t)srow[r] * 16384 + kv0 * 2 + slin[r],
                  (char*)sV[buf] + sboff[r]);
    }
  };

  const float SCL = 0.125f * 1.44269504089f;  // 1/sqrt(dk) * log2(e)
  int cur = 0;
  stage(0, 0);  // KV tile 0 is the same (kv=0..63) for both halves

#pragma unroll 1
  for (int half = 0; half < 2; ++half) {
    const int qt = half ? (31 - qp) : qp;
    const int nkv = qt + 1;

    // Q fragments: lane lr -> q-row (w*16+lr), 8 contiguous dk elems per (kk,lg)
    short8 qf[2];
    {
      const unsigned short* qbase =
          Qg + (size_t)(b * S + qt * 64 + w * 16 + lr) * D + h * 64;
      qf[0] = *reinterpret_cast<const short8*>(qbase + lg * 8);
      qf[1] = *reinterpret_cast<const short8*>(qbase + 32 + lg * 8);
    }

    f32x4 o[4] = {};
    float m = -INFINITY, lsum = 0.f;

    __syncthreads();  // drain this half's tile-0 staging

    for (int kvt = 0; kvt < nkv; ++kvt) {
      if (kvt + 1 < nkv) stage(cur ^ 1, kvt + 1);

      const char* sKc = (const char*)sK[cur];
      const char* sVc = (const char*)sV[cur];

      // S^T via swapped operands: sc[n][r] at lane (lg,lr) =
      //   S[q = w*16+lr][kv = n*16 + lg*4 + r]
      f32x4 sc[4] = {};
#pragma unroll
      for (int n = 0; n < 4; ++n) {
#pragma unroll
        for (int kk = 0; kk < 2; ++kk) {
          const int row = n * 16 + lr;
          const short8 kf = *reinterpret_cast<const short8*>(
              sKc + (row << 7) + ((kk * 64 + lg * 16) ^ ((row & 7) << 4)));
          sc[n] = __builtin_amdgcn_mfma_f32_16x16x32_bf16(kf, qf[kk], sc[n], 0, 0, 0);
        }
      }

      // scale (exp2 domain) + causal mask on the diagonal tile
      float p[4][4];
      const bool diag = (kvt == qt);
      const int ql = w * 16 + lr;
#pragma unroll
      for (int n = 0; n < 4; ++n) {
#pragma unroll
        for (int r = 0; r < 4; ++r) {
          float v = sc[n][r] * SCL;
          if (diag && (n * 16 + lg * 4 + r) > ql) v = -INFINITY;
          p[n][r] = v;
        }
      }

      // per-lane online softmax (lane owns q-row lr; 16 kv in-register,
      // full row = lanes {lr, lr+16, lr+32, lr+48} -> 2 shfl_xor)
      float mx = p[0][0];
#pragma unroll
      for (int n = 0; n < 4; ++n)
#pragma unroll
        for (int r = 0; r < 4; ++r) mx = fmaxf(mx, p[n][r]);
      mx = fmaxf(mx, __shfl_xor(mx, 16));
      mx = fmaxf(mx, __shfl_xor(mx, 32));
      const float mnew = fmaxf(m, mx);
      const float alpha = __builtin_amdgcn_exp2f(m - mnew);
      m = mnew;

      float s = 0.f;
#pragma unroll
      for (int n = 0; n < 4; ++n) {
#pragma unroll
        for (int r = 0; r < 4; ++r) {
          const float e = __builtin_amdgcn_exp2f(p[n][r] - mnew);
          p[n][r] = e;
          s += e;
        }
      }
      s += __shfl_xor(s, 16);
      s += __shfl_xor(s, 32);
      lsum = lsum * alpha + s;
#pragma unroll
      for (int dn = 0; dn < 4; ++dn) o[dn] *= alpha;

      // P -> sP (rows = q = lr): 4x ds_write_b64 (kv n*16+lg*4+0..3 contiguous)
#pragma unroll
      for (int n = 0; n < 4; ++n) {
        ushort4 pk;
        pk.x = f2bf(p[n][0]); pk.y = f2bf(p[n][1]);
        pk.z = f2bf(p[n][2]); pk.w = f2bf(p[n][3]);
        *reinterpret_cast<ushort4*>(
            (char*)sP + (w << 11) + (lr << 7) + ((n * 32 + lg * 8) ^ ((lr & 7) << 4))) = pk;
      }

      // O^T += Vt . P^T : o[dn] reg r at lane = O[q=w*16+lr][d=dn*16+lg*4+r]
#pragma unroll
      for (int kk = 0; kk < 2; ++kk) {
        const short8 pa = *reinterpret_cast<const short8*>(
            (const char*)sP + (w << 11) + (lr << 7) +
            ((kk * 64 + lg * 16) ^ ((lr & 7) << 4)));
#pragma unroll
        for (int dn = 0; dn < 4; ++dn) {
          const int vrow = dn * 16 + lr;
          const short8 vb = *reinterpret_cast<const short8*>(
              sVc + (vrow << 7) + ((kk * 64 + lg * 16) ^ ((vrow & 7) << 4)));
          o[dn] = __builtin_amdgcn_mfma_f32_16x16x32_bf16(vb, pa, o[dn], 0, 0, 0);
        }
      }

      __syncthreads();  // next buf staged (vmcnt drain); guards buf reuse
      cur ^= 1;
    }

    if (half == 0) stage(cur, 0);  // prefetch tile 0 for the paired q-tile

    // epilogue: packed 8 B stores (cols dn*16 + lg*4 + 0..3)
    const float inv = 1.f / lsum;
    unsigned short* orow = AO + (size_t)(b * S + qt * 64 + w * 16 + lr) * D + h * 64;
#pragma unroll
    for (int dn = 0; dn < 4; ++dn) {
      ushort4 ov;
      ov.x = f2bf(o[dn][0] * inv); ov.y = f2bf(o[dn][1] * inv);
      ov.z = f2bf(o[dn][2] * inv); ov.w = f2bf(o[dn][3] * inv);
      *reinterpret_cast<ushort4*>(orow + dn * 16 + lg * 4) = ov;
    }
  }
}

extern "C" void kernel_launch(void* const* d_in, const int* in_sizes, int n_in,
                              void* d_out, int out_size, void* d_ws, size_t ws_size,
                              hipStream_t stream) {
  const float* x  = (const float*)d_in[0];
  const float* Wq = (const float*)d_in[1];
  const float* Wk = (const float*)d_in[2];
  const float* Wv = (const float*)d_in[3];
  const float* Wo = (const float*)d_in[4];
  float* out = (float*)d_out;

  char* ws = (char*)d_ws;
  unsigned short* xb  = (unsigned short*)(ws);               // 8192x1024 (16 MB)
  unsigned short* Wqb = (unsigned short*)(ws + 16777216);    // 1024x1024 (2 MB)
  unsigned short* Wkb = (unsigned short*)(ws + 18874368);
  unsigned short* Wvb = (unsigned short*)(ws + 20971520);
  unsigned short* Wob = (unsigned short*)(ws + 23068672);
  unsigned short* Qb  = (unsigned short*)(ws + 25165824);    // 8192x1024
  unsigned short* Kb  = (unsigned short*)(ws + 41943040);    // 8192x1024
  unsigned short* Vt  = (unsigned short*)(ws + 58720256);    // 1024x8192 (V^T)
  unsigned short* AO  = (unsigned short*)(ws + 75497472);    // 8192x1024

  cast_f32_bf16<<<8192, 256, 0, stream>>>(x,  xb,  2097152);
  cast_f32_bf16<<<1024, 256, 0, stream>>>(Wq, Wqb, 262144);
  cast_f32_bf16<<<1024, 256, 0, stream>>>(Wk, Wkb, 262144);
  cast_f32_bf16<<<1024, 256, 0, stream>>>(Wv, Wvb, 262144);
  cast_f32_bf16<<<1024, 256, 0, stream>>>(Wo, Wob, 262144);

  const dim3 blk(256);
  gemm_nt<unsigned short><<<dim3(8, 64), blk, 0, stream>>>(xb, Wqb, Qb, 8192, 1024, 1024);
  gemm_nt<unsigned short><<<dim3(8, 64), blk, 0, stream>>>(xb, Wkb, Kb, 8192, 1024, 1024);
  gemm_nt<unsigned short><<<dim3(64, 8), blk, 0, stream>>>(Wvb, xb, Vt, 1024, 8192, 1024);

  attn_kernel<<<dim3(1024), blk, 0, stream>>>(Qb, Kb, Vt, AO);

  gemm_nt<float><<<dim3(8, 64), blk, 0, stream>>>(AO, Wob, out, 8192, 1024, 1024);
}

// Round 4
// 286.116 us; speedup vs baseline: 1.6715x; 1.0090x over previous
//
#include <hip/hip_runtime.h>
#include <hip/hip_bf16.h>
#include <stdint.h>

typedef __attribute__((ext_vector_type(8))) short short8;
typedef __attribute__((ext_vector_type(4))) float f32x4;

static __device__ __forceinline__ void gload_lds16(const void* g, void* l) {
  __builtin_amdgcn_global_load_lds((const __attribute__((address_space(1))) void*)g,
                                   (__attribute__((address_space(3))) void*)l,
                                   16, 0, 0);
}

static __device__ __forceinline__ unsigned short f2bf(float f) {
  union { __hip_bfloat16 h; unsigned short s; } u;
  u.h = __float2bfloat16(f);
  return u.s;
}

// One fused cast: x (2097152 float4s) then Wq/Wk/Wv/Wo (262144 float4s each).
// Regions are multiples of 256 quads, so no block straddles a region.
__global__ void cast_all(const float* __restrict__ x, const float* __restrict__ Wq,
                         const float* __restrict__ Wk, const float* __restrict__ Wv,
                         const float* __restrict__ Wo,
                         unsigned short* __restrict__ xb, unsigned short* __restrict__ Wqb,
                         unsigned short* __restrict__ Wkb, unsigned short* __restrict__ Wvb,
                         unsigned short* __restrict__ Wob) {
  const int i = blockIdx.x * 256 + threadIdx.x;
  const float* src;
  unsigned short* dst;
  int off;
  if (i < 2097152) {
    src = x; dst = xb; off = i;
  } else {
    const int j = i - 2097152;
    const int wsel = j >> 18;
    off = j & 262143;
    src = wsel == 0 ? Wq : wsel == 1 ? Wk : wsel == 2 ? Wv : Wo;
    dst = wsel == 0 ? Wqb : wsel == 1 ? Wkb : wsel == 2 ? Wvb : Wob;
  }
  float4 v = reinterpret_cast<const float4*>(src)[off];
  ushort4 o;
  o.x = f2bf(v.x); o.y = f2bf(v.y); o.z = f2bf(v.z); o.w = f2bf(v.w);
  reinterpret_cast<ushort4*>(dst)[off] = o;
}

// Shared 128x128-tile 2-phase GEMM body, K=1024 fixed, row-major A[.,1024],
// B[.,1024]; C[rr*ldc+cc]. m97 structure: dbuf LDS, stage(next) before
// compute(cur), one barrier per K-step, global_load_lds width 16.
template <typename OutT>
static __device__ __forceinline__ void gemm_tile(const unsigned short* __restrict__ A,
                                                 const unsigned short* __restrict__ B,
                                                 OutT* __restrict__ C,
                                                 int brow, int bcol, int ldc,
                                                 short* sA0, short* sA1,
                                                 short* sB0, short* sB1) {
  const int t = threadIdx.x;
  const int w = t >> 6, l = t & 63, lg = l >> 4, lr = l & 15;
  const int wr = w >> 1, wc = w & 1;
  short* sAb[2] = {sA0, sA1};
  short* sBb[2] = {sB0, sB1};

  f32x4 acc[4][4] = {};

  auto stage = [&](int buf, int kt) {
#pragma unroll
    for (int r = 0; r < 2; ++r) {
      const int byteoff = t * 16 + r * 4096;
      const int row = byteoff >> 6, inrow = byteoff & 63;  // 64 B per row (32 bf16)
      gload_lds16((const char*)A + ((size_t)(brow + row) * 1024 + kt) * 2 + inrow,
                  (char*)sAb[buf] + byteoff);
      gload_lds16((const char*)B + ((size_t)(bcol + row) * 1024 + kt) * 2 + inrow,
                  (char*)sBb[buf] + byteoff);
    }
  };

  stage(0, 0);
  __syncthreads();
  int cur = 0;

  for (int kti = 0; kti < 32; ++kti) {
    if (kti + 1 < 32) stage(cur ^ 1, (kti + 1) << 5);

    short8 af[4], bfr[4];
#pragma unroll
    for (int m = 0; m < 4; ++m)
      af[m] = *reinterpret_cast<const short8*>(sAb[cur] + (wr * 64 + m * 16 + lr) * 32 + lg * 8);
#pragma unroll
    for (int n = 0; n < 4; ++n)
      bfr[n] = *reinterpret_cast<const short8*>(sBb[cur] + (wc * 64 + n * 16 + lr) * 32 + lg * 8);
#pragma unroll
    for (int m = 0; m < 4; ++m)
#pragma unroll
      for (int n = 0; n < 4; ++n)
        acc[m][n] = __builtin_amdgcn_mfma_f32_16x16x32_bf16(af[m], bfr[n], acc[m][n], 0, 0, 0);

    __syncthreads();  // drains prefetch vmcnt; guards buffer reuse
    cur ^= 1;
  }

  // C/D layout: col = lane&15, row = (lane>>4)*4 + reg  [m89 verified]
#pragma unroll
  for (int m = 0; m < 4; ++m) {
#pragma unroll
    for (int n = 0; n < 4; ++n) {
#pragma unroll
      for (int j = 0; j < 4; ++j) {
        const int rr = brow + wr * 64 + m * 16 + lg * 4 + j;
        const int cc = bcol + wc * 64 + n * 16 + lr;
        if constexpr (sizeof(OutT) == 2) {
          C[(size_t)rr * ldc + cc] = (OutT)f2bf(acc[m][n][j]);
        } else {
          C[(size_t)rr * ldc + cc] = acc[m][n][j];
        }
      }
    }
  }
}

// Fused Q/K/V projections: 1536 blocks, XCD-chunked.
// z=0: Q = x Wq^T [8192,1024]; z=1: K = x Wk^T; z=2: Vt = Wv x^T [1024,8192].
__global__ __launch_bounds__(256) void gemm_qkv(const unsigned short* __restrict__ xb,
                                                const unsigned short* __restrict__ Wqb,
                                                const unsigned short* __restrict__ Wkb,
                                                const unsigned short* __restrict__ Wvb,
                                                unsigned short* __restrict__ Qb,
                                                unsigned short* __restrict__ Kb,
                                                unsigned short* __restrict__ Vt) {
  __shared__ short sA[2][4096];
  __shared__ short sB[2][4096];
  const int i = blockIdx.x;
  const int lid = (i & 7) * 192 + (i >> 3);  // bijective: 1536 = 8*192
  const int z = lid >> 9, r = lid & 511;

  const unsigned short *A, *B;
  unsigned short* C;
  int brow, bcol, ldc;
  if (z == 2) {
    A = Wvb; B = xb; C = Vt;
    brow = (r & 7) << 7; bcol = (r >> 3) << 7; ldc = 8192;
  } else {
    A = xb; B = z ? Wkb : Wqb; C = z ? Kb : Qb;
    brow = (r >> 3) << 7; bcol = (r & 7) << 7; ldc = 1024;
  }
  gemm_tile<unsigned short>(A, B, C, brow, bcol, ldc, sA[0], sA[1], sB[0], sB[1]);
}

// Final projection: out = AO Wo^T, f32 out. 512 blocks, XCD-chunked.
__global__ __launch_bounds__(256) void gemm_out(const unsigned short* __restrict__ AO,
                                                const unsigned short* __restrict__ Wob,
                                                float* __restrict__ out) {
  __shared__ short sA[2][4096];
  __shared__ short sB[2][4096];
  const int i = blockIdx.x;
  const int lid = (i & 7) * 64 + (i >> 3);  // bijective: 512 = 8*64
  gemm_tile<float>(AO, Wob, out, (lid >> 3) << 7, (lid & 7) << 7, 1024,
                   sA[0], sA[1], sB[0], sB[1]);
}

// Causal flash attention, swapped-QK^T per-lane softmax, paired q-tiles,
// defer-max (T13) + setprio around MFMA clusters (T5).
__global__ __launch_bounds__(256) void attn_kernel(const unsigned short* __restrict__ Qg,
                                                   const unsigned short* __restrict__ Kg,
                                                   const unsigned short* __restrict__ Vtg,
                                                   unsigned short* __restrict__ AO) {
  const int S = 2048, D = 1024, SN = 8192;  // SN = B*S
  const int i = blockIdx.x;
  const int lid = (i & 7) * 128 + (i >> 3);  // XCD k <- lids [128k,128k+128)
  const int qp = lid & 15;
  const int bh = lid >> 4;
  const int b = bh >> 4, h = bh & 15;
  const int t = threadIdx.x;
  const int w = t >> 6, l = t & 63, lg = l >> 4, lr = l & 15;

  __shared__ short sK[2][64 * 64];  // [kv][dk], XOR-swizzled rows (128 B/row)
  __shared__ short sV[2][64 * 64];  // [dk][kv] (=V^T), XOR-swizzled
  __shared__ short sP[4 * 16 * 64]; // per-wave P[q=16][kv=64], XOR-swizzled

  int sboff[2], slin[2], srow[2];
#pragma unroll
  for (int r = 0; r < 2; ++r) {
    sboff[r] = t * 16 + r * 4096;
    srow[r] = sboff[r] >> 7;                 // 128 B per row
    slin[r] = (sboff[r] & 127) ^ ((srow[r] & 7) << 4);  // inverse-swizzled source
  }
  const char* Kbase = (const char*)Kg + ((size_t)(b * S) * D + h * 64) * 2;
  const char* Vbase = (const char*)Vtg + ((size_t)(h * 64) * SN + (size_t)b * S) * 2;

  auto stage = [&](int buf, int kvt) {
    const size_t kv0 = (size_t)kvt * 64;
#pragma unroll
    for (int r = 0; r < 2; ++r) {
      gload_lds16(Kbase + (kv0 + srow[r]) * 2048 + slin[r], (char*)sK[buf] + sboff[r]);
      gload_lds16(Vbase + (size_t)srow[r] * 16384 + kv0 * 2 + slin[r],
                  (char*)sV[buf] + sboff[r]);
    }
  };

  const float SCL = 0.125f * 1.44269504089f;  // 1/sqrt(dk) * log2(e)
  int cur = 0;
  stage(0, 0);  // KV tile 0 is shared by both halves

#pragma unroll 1
  for (int half = 0; half < 2; ++half) {
    const int qt = half ? (31 - qp) : qp;
    const int nkv = qt + 1;

    short8 qf[2];
    {
      const unsigned short* qbase =
          Qg + (size_t)(b * S + qt * 64 + w * 16 + lr) * D + h * 64;
      qf[0] = *reinterpret_cast<const short8*>(qbase + lg * 8);
      qf[1] = *reinterpret_cast<const short8*>(qbase + 32 + lg * 8);
    }

    f32x4 o[4] = {};
    float m = -INFINITY, lsum = 0.f;

    __syncthreads();  // drain this half's tile-0 staging

    for (int kvt = 0; kvt < nkv; ++kvt) {
      if (kvt + 1 < nkv) stage(cur ^ 1, kvt + 1);

      const char* sKc = (const char*)sK[cur];
      const char* sVc = (const char*)sV[cur];

      // S^T via swapped operands: sc[n][r] at lane (lg,lr) =
      //   S[q = w*16+lr][kv = n*16 + lg*4 + r]
      f32x4 sc[4] = {};
      __builtin_amdgcn_s_setprio(1);
#pragma unroll
      for (int n = 0; n < 4; ++n) {
#pragma unroll
        for (int kk = 0; kk < 2; ++kk) {
          const int row = n * 16 + lr;
          const short8 kf = *reinterpret_cast<const short8*>(
              sKc + (row << 7) + ((kk * 64 + lg * 16) ^ ((row & 7) << 4)));
          sc[n] = __builtin_amdgcn_mfma_f32_16x16x32_bf16(kf, qf[kk], sc[n], 0, 0, 0);
        }
      }
      __builtin_amdgcn_s_setprio(0);

      // scale (exp2 domain) + causal mask on the diagonal tile
      float p[4][4];
      const bool diag = (kvt == qt);
      const int ql = w * 16 + lr;
#pragma unroll
      for (int n = 0; n < 4; ++n) {
#pragma unroll
        for (int r = 0; r < 4; ++r) {
          float v = sc[n][r] * SCL;
          if (diag && (n * 16 + lg * 4 + r) > ql) v = -INFINITY;
          p[n][r] = v;
        }
      }

      // per-lane online softmax with defer-max (T13, THR=8 in log2 domain):
      // row = q-row lr; full row lives in lanes {lr, lr+16, lr+32, lr+48}.
      float mx = p[0][0];
#pragma unroll
      for (int n = 0; n < 4; ++n)
#pragma unroll
        for (int r = 0; r < 4; ++r) mx = fmaxf(mx, p[n][r]);
      mx = fmaxf(mx, __shfl_xor(mx, 16));
      mx = fmaxf(mx, __shfl_xor(mx, 32));
      if (!__all(mx <= m + 8.0f)) {
        const float mnew = fmaxf(m, mx);
        const float alpha = __builtin_amdgcn_exp2f(m - mnew);
        m = mnew;
        lsum *= alpha;
#pragma unroll
        for (int dn = 0; dn < 4; ++dn) o[dn] *= alpha;
      }

      float s = 0.f;
#pragma unroll
      for (int n = 0; n < 4; ++n) {
#pragma unroll
        for (int r = 0; r < 4; ++r) {
          const float e = __builtin_amdgcn_exp2f(p[n][r] - m);
          p[n][r] = e;
          s += e;
        }
      }
      s += __shfl_xor(s, 16);
      s += __shfl_xor(s, 32);
      lsum += s;

      // P -> sP (rows = q = lr): 4x ds_write_b64
#pragma unroll
      for (int n = 0; n < 4; ++n) {
        ushort4 pk;
        pk.x = f2bf(p[n][0]); pk.y = f2bf(p[n][1]);
        pk.z = f2bf(p[n][2]); pk.w = f2bf(p[n][3]);
        *reinterpret_cast<ushort4*>(
            (char*)sP + (w << 11) + (lr << 7) + ((n * 32 + lg * 8) ^ ((lr & 7) << 4))) = pk;
      }

      // O^T += Vt . P^T : o[dn] reg r at lane = O[q=w*16+lr][d=dn*16+lg*4+r]
      __builtin_amdgcn_s_setprio(1);
#pragma unroll
      for (int kk = 0; kk < 2; ++kk) {
        const short8 pa = *reinterpret_cast<const short8*>(
            (const char*)sP + (w << 11) + (lr << 7) +
            ((kk * 64 + lg * 16) ^ ((lr & 7) << 4)));
#pragma unroll
        for (int dn = 0; dn < 4; ++dn) {
          const int vrow = dn * 16 + lr;
          const short8 vb = *reinterpret_cast<const short8*>(
              sVc + (vrow << 7) + ((kk * 64 + lg * 16) ^ ((vrow & 7) << 4)));
          o[dn] = __builtin_amdgcn_mfma_f32_16x16x32_bf16(vb, pa, o[dn], 0, 0, 0);
        }
      }
      __builtin_amdgcn_s_setprio(0);

      __syncthreads();  // next buf staged (vmcnt drain); guards buf reuse
      cur ^= 1;
    }

    if (half == 0) stage(cur, 0);  // prefetch tile 0 for the paired q-tile

    const float inv = 1.f / lsum;
    unsigned short* orow = AO + (size_t)(b * S + qt * 64 + w * 16 + lr) * D + h * 64;
#pragma unroll
    for (int dn = 0; dn < 4; ++dn) {
      ushort4 ov;
      ov.x = f2bf(o[dn][0] * inv); ov.y = f2bf(o[dn][1] * inv);
      ov.z = f2bf(o[dn][2] * inv); ov.w = f2bf(o[dn][3] * inv);
      *reinterpret_cast<ushort4*>(orow + dn * 16 + lg * 4) = ov;
    }
  }
}

extern "C" void kernel_launch(void* const* d_in, const int* in_sizes, int n_in,
                              void* d_out, int out_size, void* d_ws, size_t ws_size,
                              hipStream_t stream) {
  const float* x  = (const float*)d_in[0];
  const float* Wq = (const float*)d_in[1];
  const float* Wk = (const float*)d_in[2];
  const float* Wv = (const float*)d_in[3];
  const float* Wo = (const float*)d_in[4];
  float* out = (float*)d_out;

  char* ws = (char*)d_ws;
  unsigned short* xb  = (unsigned short*)(ws);               // 8192x1024 (16 MB)
  unsigned short* Wqb = (unsigned short*)(ws + 16777216);    // 1024x1024 (2 MB)
  unsigned short* Wkb = (unsigned short*)(ws + 18874368);
  unsigned short* Wvb = (unsigned short*)(ws + 20971520);
  unsigned short* Wob = (unsigned short*)(ws + 23068672);
  unsigned short* Qb  = (unsigned short*)(ws + 25165824);    // 8192x1024
  unsigned short* Kb  = (unsigned short*)(ws + 41943040);    // 8192x1024
  unsigned short* Vt  = (unsigned short*)(ws + 58720256);    // 1024x8192 (V^T)
  unsigned short* AO  = (unsigned short*)(ws + 75497472);    // 8192x1024

  cast_all<<<12288, 256, 0, stream>>>(x, Wq, Wk, Wv, Wo, xb, Wqb, Wkb, Wvb, Wob);
  gemm_qkv<<<1536, 256, 0, stream>>>(xb, Wqb, Wkb, Wvb, Qb, Kb, Vt);
  attn_kernel<<<1024, 256, 0, stream>>>(Qb, Kb, Vt, AO);
  gemm_out<<<512, 256, 0, stream>>>(AO, Wob, out);
}

// Round 6
// 274.017 us; speedup vs baseline: 1.7453x; 1.0442x over previous
//
#include <hip/hip_runtime.h>
#include <hip/hip_bf16.h>
#include <stdint.h>

typedef __attribute__((ext_vector_type(8))) short short8;
typedef __attribute__((ext_vector_type(4))) float f32x4;

static __device__ __forceinline__ void gload_lds16(const void* g, void* l) {
  __builtin_amdgcn_global_load_lds((const __attribute__((address_space(1))) void*)g,
                                   (__attribute__((address_space(3))) void*)l,
                                   16, 0, 0);
}

static __device__ __forceinline__ unsigned short f2bf(float f) {
  union { __hip_bfloat16 h; unsigned short s; } u;
  u.h = __float2bfloat16(f);
  return u.s;
}

// Counted waits + raw barrier in ONE asm (memory-clobber fences IR motion).
#define WAIT4_BARRIER() asm volatile("s_waitcnt vmcnt(4) lgkmcnt(0)\n\ts_barrier" ::: "memory")
#define WAIT0_BARRIER() asm volatile("s_waitcnt vmcnt(0) lgkmcnt(0)\n\ts_barrier" ::: "memory")

// One fused cast: x (2097152 float4s) then Wq/Wk/Wv/Wo (262144 float4s each).
__global__ void cast_all(const float* __restrict__ x, const float* __restrict__ Wq,
                         const float* __restrict__ Wk, const float* __restrict__ Wv,
                         const float* __restrict__ Wo,
                         unsigned short* __restrict__ xb, unsigned short* __restrict__ Wqb,
                         unsigned short* __restrict__ Wkb, unsigned short* __restrict__ Wvb,
                         unsigned short* __restrict__ Wob) {
  const int i = blockIdx.x * 256 + threadIdx.x;
  const float* src;
  unsigned short* dst;
  int off;
  if (i < 2097152) {
    src = x; dst = xb; off = i;
  } else {
    const int j = i - 2097152;
    const int wsel = j >> 18;
    off = j & 262143;
    src = wsel == 0 ? Wq : wsel == 1 ? Wk : wsel == 2 ? Wv : Wo;
    dst = wsel == 0 ? Wqb : wsel == 1 ? Wkb : wsel == 2 ? Wvb : Wob;
  }
  float4 v = reinterpret_cast<const float4*>(src)[off];
  ushort4 o;
  o.x = f2bf(v.x); o.y = f2bf(v.y); o.z = f2bf(v.z); o.w = f2bf(v.w);
  reinterpret_cast<ushort4*>(dst)[off] = o;
}

// 128x128-tile GEMM body, K=1024, NT (A[M,1024] x B[N,1024]^T).
// Triple-buffered LDS (lookahead-2 staging), counted vmcnt(4) + raw barrier
// (one per K-step, never draining to 0 mid-loop), T2 XOR-swizzled LDS.
// Swizzle for 64B rows: s(row) = ((row>>1)&3)<<4 — maps rows 0..7 to all 8
// bank-groups (group = 4*(r&1) + (r>>1)&3 mod 8 = bijective), conflict-free.
template <typename OutT>
static __device__ __forceinline__ void gemm_tile(const unsigned short* __restrict__ A,
                                                 const unsigned short* __restrict__ B,
                                                 OutT* __restrict__ C,
                                                 int brow, int bcol, int ldc,
                                                 short* sA, short* sB) {
  const int t = threadIdx.x;
  const int w = t >> 6, l = t & 63, lg = l >> 4, lr = l & 15;
  const int wr = w >> 1, wc = w & 1;

  f32x4 acc[4][4] = {};

  auto stage = [&](int buf, int kt) {
#pragma unroll
    for (int r = 0; r < 2; ++r) {
      const int byteoff = t * 16 + r * 4096;      // 8 KB per matrix-tile
      const int row = byteoff >> 6;               // 64 B per row (32 bf16)
      const int inrow = (byteoff & 63) ^ (((row >> 1) & 3) << 4);  // inv-swz src
      gload_lds16((const char*)A + ((size_t)(brow + row) * 1024 + kt) * 2 + inrow,
                  (char*)(sA + buf * 4096) + byteoff);
      gload_lds16((const char*)B + ((size_t)(bcol + row) * 1024 + kt) * 2 + inrow,
                  (char*)(sB + buf * 4096) + byteoff);
    }
  };

  stage(0, 0);
  stage(1, 32);
  int cur = 0;

  for (int kti = 0; kti < 32; ++kti) {
    if (kti < 31) WAIT4_BARRIER();  // tile kti landed; tile kti+1 stays in flight
    else         WAIT0_BARRIER();
    if (kti + 2 < 32) {
      int b2 = cur + 2; if (b2 >= 3) b2 -= 3;
      stage(b2, (kti + 2) << 5);
    }
    const char* sAc = (const char*)(sA + cur * 4096);
    const char* sBc = (const char*)(sB + cur * 4096);

    short8 af[4], bfr[4];
#pragma unroll
    for (int m = 0; m < 4; ++m) {
      const int arow = wr * 64 + m * 16 + lr;
      af[m] = *reinterpret_cast<const short8*>(
          sAc + arow * 64 + ((lg * 16) ^ (((arow >> 1) & 3) << 4)));
    }
#pragma unroll
    for (int n = 0; n < 4; ++n) {
      const int brw = wc * 64 + n * 16 + lr;
      bfr[n] = *reinterpret_cast<const short8*>(
          sBc + brw * 64 + ((lg * 16) ^ (((brw >> 1) & 3) << 4)));
    }
    __builtin_amdgcn_s_setprio(1);
#pragma unroll
    for (int m = 0; m < 4; ++m)
#pragma unroll
      for (int n = 0; n < 4; ++n)
        acc[m][n] = __builtin_amdgcn_mfma_f32_16x16x32_bf16(af[m], bfr[n], acc[m][n], 0, 0, 0);
    __builtin_amdgcn_s_setprio(0);

    ++cur; if (cur == 3) cur = 0;
  }

  // C/D layout: col = lane&15, row = (lane>>4)*4 + reg  [m89 verified]
#pragma unroll
  for (int m = 0; m < 4; ++m) {
#pragma unroll
    for (int n = 0; n < 4; ++n) {
#pragma unroll
      for (int j = 0; j < 4; ++j) {
        const int rr = brow + wr * 64 + m * 16 + lg * 4 + j;
        const int cc = bcol + wc * 64 + n * 16 + lr;
        if constexpr (sizeof(OutT) == 2) {
          C[(size_t)rr * ldc + cc] = (OutT)f2bf(acc[m][n][j]);
        } else {
          C[(size_t)rr * ldc + cc] = acc[m][n][j];
        }
      }
    }
  }
}

// Fused Q/K/V projections: 1536 blocks, XCD-chunked.
__global__ __launch_bounds__(256) void gemm_qkv(const unsigned short* __restrict__ xb,
                                                const unsigned short* __restrict__ Wqb,
                                                const unsigned short* __restrict__ Wkb,
                                                const unsigned short* __restrict__ Wvb,
                                                unsigned short* __restrict__ Qb,
                                                unsigned short* __restrict__ Kb,
                                                unsigned short* __restrict__ Vt) {
  __shared__ short sA[3][4096];
  __shared__ short sB[3][4096];
  const int i = blockIdx.x;
  const int lid = (i & 7) * 192 + (i >> 3);  // bijective: 1536 = 8*192
  const int z = lid >> 9, r = lid & 511;

  const unsigned short *A, *B;
  unsigned short* C;
  int brow, bcol, ldc;
  if (z == 2) {
    A = Wvb; B = xb; C = Vt;
    brow = (r & 7) << 7; bcol = (r >> 3) << 7; ldc = 8192;
  } else {
    A = xb; B = z ? Wkb : Wqb; C = z ? Kb : Qb;
    brow = (r >> 3) << 7; bcol = (r & 7) << 7; ldc = 1024;
  }
  gemm_tile<unsigned short>(A, B, C, brow, bcol, ldc, sA[0], sB[0]);
}

// Final projection: out = AO Wo^T, f32 out. 512 blocks, XCD-chunked.
__global__ __launch_bounds__(256) void gemm_out(const unsigned short* __restrict__ AO,
                                                const unsigned short* __restrict__ Wob,
                                                float* __restrict__ out) {
  __shared__ short sA[3][4096];
  __shared__ short sB[3][4096];
  const int i = blockIdx.x;
  const int lid = (i & 7) * 64 + (i >> 3);  // bijective: 512 = 8*64
  gemm_tile<float>(AO, Wob, out, (lid >> 3) << 7, (lid & 7) << 7, 1024, sA[0], sB[0]);
}

// Causal flash attention: swapped-QK^T per-lane softmax, paired q-tiles
// flattened into one 33-tile sequence, triple-buffered K/V with counted
// vmcnt(4) + raw barrier (one per tile), defer-max, setprio.
__global__ __launch_bounds__(256) void attn_kernel(const unsigned short* __restrict__ Qg,
                                                   const unsigned short* __restrict__ Kg,
                                                   const unsigned short* __restrict__ Vtg,
                                                   unsigned short* __restrict__ AO) {
  const int S = 2048, D = 1024, SN = 8192;
  const int i = blockIdx.x;
  const int lid = (i & 7) * 128 + (i >> 3);  // XCD k <- lids [128k,128k+128)
  const int qp = lid & 15;
  const int bh = lid >> 4;
  const int b = bh >> 4, h = bh & 15;
  const int t = threadIdx.x;
  const int w = t >> 6, l = t & 63, lg = l >> 4, lr = l & 15;

  __shared__ short sK[3][4096];  // [kv=64][dk=64], XOR-swizzled 128B rows
  __shared__ short sV[3][4096];  // [dk=64][kv=64] (=V^T), XOR-swizzled
  __shared__ short sP[4096];     // per-wave P[q=16][kv=64], XOR-swizzled

  int sboff[2], slin[2], srow[2];
#pragma unroll
  for (int r = 0; r < 2; ++r) {
    sboff[r] = t * 16 + r * 4096;
    srow[r] = sboff[r] >> 7;                            // 128 B per row
    slin[r] = (sboff[r] & 127) ^ ((srow[r] & 7) << 4);  // inverse-swizzled src
  }
  const char* Kbase = (const char*)Kg + ((size_t)(b * S) * D + h * 64) * 2;
  const char* Vbase = (const char*)Vtg + ((size_t)(h * 64) * SN + (size_t)b * S) * 2;

  const int nkv0 = qp + 1;       // half0: qt=qp, tiles 0..qp
  const int qt1 = 31 - qp;       // half1: qt=31-qp, tiles 0..31-qp (33 total)

  auto stage = [&](int buf, int j) {
    const int kvt = (j < nkv0) ? j : j - nkv0;
    const size_t kv0 = (size_t)kvt * 64;
#pragma unroll
    for (int r = 0; r < 2; ++r) {
      gload_lds16(Kbase + (kv0 + srow[r]) * 2048 + slin[r],
                  (char*)sK + buf * 8192 + sboff[r]);
      gload_lds16(Vbase + (size_t)srow[r] * 16384 + kv0 * 2 + slin[r],
                  (char*)sV + buf * 8192 + sboff[r]);
    }
  };
  auto load_qf = [&](int qt, short8* qf) {
    const unsigned short* qbase =
        Qg + (size_t)(b * S + qt * 64 + w * 16 + lr) * D + h * 64;
    qf[0] = *reinterpret_cast<const short8*>(qbase + lg * 8);
    qf[1] = *reinterpret_cast<const short8*>(qbase + 32 + lg * 8);
  };

  const float SCL = 0.125f * 1.44269504089f;  // 1/sqrt(dk) * log2(e)

  short8 qf[2];
  load_qf(qp, qf);     // issued before staging: vmcnt-oldest, retires first
  stage(0, 0);
  stage(1, 1);

  f32x4 o[4] = {};
  float m = -INFINITY, lsum = 0.f;
  int cur = 0;

  auto epilogue = [&](int qt) {
    const float inv = 1.f / lsum;
    unsigned short* orow = AO + (size_t)(b * S + qt * 64 + w * 16 + lr) * D + h * 64;
#pragma unroll
    for (int dn = 0; dn < 4; ++dn) {
      ushort4 ov;
      ov.x = f2bf(o[dn][0] * inv); ov.y = f2bf(o[dn][1] * inv);
      ov.z = f2bf(o[dn][2] * inv); ov.w = f2bf(o[dn][3] * inv);
      *reinterpret_cast<ushort4*>(orow + dn * 16 + lg * 4) = ov;
    }
  };

#pragma unroll 1
  for (int j = 0; j < 33; ++j) {
    const bool h1 = (j >= nkv0);
    const int kvt = h1 ? j - nkv0 : j;
    const int qt = h1 ? qt1 : qp;

    if (j < 32) WAIT4_BARRIER();  // tile j landed; tile j+1 stays in flight
    else        WAIT0_BARRIER();
    if (j + 2 < 33) {
      int b2 = cur + 2; if (b2 >= 3) b2 -= 3;
      stage(b2, j + 2);
    }

    const char* sKc = (const char*)sK + cur * 8192;
    const char* sVc = (const char*)sV + cur * 8192;

    // S^T via swapped operands: sc[n][r] at lane (lg,lr) =
    //   S[q = w*16+lr][kv = n*16 + lg*4 + r]
    f32x4 sc[4] = {};
    __builtin_amdgcn_s_setprio(1);
#pragma unroll
    for (int n = 0; n < 4; ++n) {
#pragma unroll
      for (int kk = 0; kk < 2; ++kk) {
        const int row = n * 16 + lr;
        const short8 kf = *reinterpret_cast<const short8*>(
            sKc + (row << 7) + ((kk * 64 + lg * 16) ^ ((row & 7) << 4)));
        sc[n] = __builtin_amdgcn_mfma_f32_16x16x32_bf16(kf, qf[kk], sc[n], 0, 0, 0);
      }
    }
    __builtin_amdgcn_s_setprio(0);

    float p[4][4];
    const bool diag = (kvt == qt);
    const int ql = w * 16 + lr;
#pragma unroll
    for (int n = 0; n < 4; ++n) {
#pragma unroll
      for (int r = 0; r < 4; ++r) {
        float v = sc[n][r] * SCL;
        if (diag && (n * 16 + lg * 4 + r) > ql) v = -INFINITY;
        p[n][r] = v;
      }
    }

    // per-lane online softmax with defer-max (T13, THR=8 in log2 domain)
    float mx = p[0][0];
#pragma unroll
    for (int n = 0; n < 4; ++n)
#pragma unroll
      for (int r = 0; r < 4; ++r) mx = fmaxf(mx, p[n][r]);
    mx = fmaxf(mx, __shfl_xor(mx, 16));
    mx = fmaxf(mx, __shfl_xor(mx, 32));
    if (!__all(mx <= m + 8.0f)) {
      const float mnew = fmaxf(m, mx);
      const float alpha = __builtin_amdgcn_exp2f(m - mnew);
      m = mnew;
      lsum *= alpha;
#pragma unroll
      for (int dn = 0; dn < 4; ++dn) o[dn] *= alpha;
    }

    float s = 0.f;
#pragma unroll
    for (int n = 0; n < 4; ++n) {
#pragma unroll
      for (int r = 0; r < 4; ++r) {
        const float e = __builtin_amdgcn_exp2f(p[n][r] - m);
        p[n][r] = e;
        s += e;
      }
    }
    s += __shfl_xor(s, 16);
    s += __shfl_xor(s, 32);
    lsum += s;

    // P -> sP (rows = q = lr), wave-private (no barrier; same-wave lgkm order)
#pragma unroll
    for (int n = 0; n < 4; ++n) {
      ushort4 pk;
      pk.x = f2bf(p[n][0]); pk.y = f2bf(p[n][1]);
      pk.z = f2bf(p[n][2]); pk.w = f2bf(p[n][3]);
      *reinterpret_cast<ushort4*>(
          (char*)sP + (w << 11) + (lr << 7) + ((n * 32 + lg * 8) ^ ((lr & 7) << 4))) = pk;
    }

    // O^T += Vt . P^T
    __builtin_amdgcn_s_setprio(1);
#pragma unroll
    for (int kk = 0; kk < 2; ++kk) {
      const short8 pa = *reinterpret_cast<const short8*>(
          (const char*)sP + (w << 11) + (lr << 7) +
          ((kk * 64 + lg * 16) ^ ((lr & 7) << 4)));
#pragma unroll
      for (int dn = 0; dn < 4; ++dn) {
        const int vrow = dn * 16 + lr;
        const short8 vb = *reinterpret_cast<const short8*>(
            sVc + (vrow << 7) + ((kk * 64 + lg * 16) ^ ((vrow & 7) << 4)));
        o[dn] = __builtin_amdgcn_mfma_f32_16x16x32_bf16(vb, pa, o[dn], 0, 0, 0);
      }
    }
    __builtin_amdgcn_s_setprio(0);

    if (j == nkv0 - 1) {  // end of half0: store, reset, reload Q for half1
      epilogue(qp);
#pragma unroll
      for (int dn = 0; dn < 4; ++dn) o[dn] = f32x4{0.f, 0.f, 0.f, 0.f};
      m = -INFINITY; lsum = 0.f;
      load_qf(qt1, qf);
    }

    ++cur; if (cur == 3) cur = 0;
  }
  epilogue(qt1);
}

extern "C" void kernel_launch(void* const* d_in, const int* in_sizes, int n_in,
                              void* d_out, int out_size, void* d_ws, size_t ws_size,
                              hipStream_t stream) {
  const float* x  = (const float*)d_in[0];
  const float* Wq = (const float*)d_in[1];
  const float* Wk = (const float*)d_in[2];
  const float* Wv = (const float*)d_in[3];
  const float* Wo = (const float*)d_in[4];
  float* out = (float*)d_out;

  char* ws = (char*)d_ws;
  unsigned short* xb  = (unsigned short*)(ws);               // 8192x1024 (16 MB)
  unsigned short* Wqb = (unsigned short*)(ws + 16777216);
  unsigned short* Wkb = (unsigned short*)(ws + 18874368);
  unsigned short* Wvb = (unsigned short*)(ws + 20971520);
  unsigned short* Wob = (unsigned short*)(ws + 23068672);
  unsigned short* Qb  = (unsigned short*)(ws + 25165824);    // 8192x1024
  unsigned short* Kb  = (unsigned short*)(ws + 41943040);    // 8192x1024
  unsigned short* Vt  = (unsigned short*)(ws + 58720256);    // 1024x8192 (V^T)
  unsigned short* AO  = (unsigned short*)(ws + 75497472);    // 8192x1024

  cast_all<<<12288, 256, 0, stream>>>(x, Wq, Wk, Wv, Wo, xb, Wqb, Wkb, Wvb, Wob);
  gemm_qkv<<<1536, 256, 0, stream>>>(xb, Wqb, Wkb, Wvb, Qb, Kb, Vt);
  attn_kernel<<<1024, 256, 0, stream>>>(Qb, Kb, Vt, AO);
  gemm_out<<<512, 256, 0, stream>>>(AO, Wob, out);
}

// Round 7
// 254.134 us; speedup vs baseline: 1.8819x; 1.0782x over previous
//
#include <hip/hip_runtime.h>
#include <hip/hip_bf16.h>
#include <stdint.h>

typedef __attribute__((ext_vector_type(8))) short short8;
typedef __attribute__((ext_vector_type(4))) float f32x4;

static __device__ __forceinline__ void gload_lds16(const void* g, void* l) {
  __builtin_amdgcn_global_load_lds((const __attribute__((address_space(1))) void*)g,
                                   (__attribute__((address_space(3))) void*)l,
                                   16, 0, 0);
}

static __device__ __forceinline__ unsigned short f2bf(float f) {
  union { __hip_bfloat16 h; unsigned short s; } u;
  u.h = __float2bfloat16(f);
  return u.s;
}

// Counted waits + raw barrier in ONE asm (memory-clobber fences IR motion).
#define WAIT4_BARRIER() asm volatile("s_waitcnt vmcnt(4) lgkmcnt(0)\n\ts_barrier" ::: "memory")
#define WAIT0_BARRIER() asm volatile("s_waitcnt vmcnt(0) lgkmcnt(0)\n\ts_barrier" ::: "memory")

// One fused cast: x (2097152 float4s) then Wq/Wk/Wv/Wo (262144 float4s each).
__global__ void cast_all(const float* __restrict__ x, const float* __restrict__ Wq,
                         const float* __restrict__ Wk, const float* __restrict__ Wv,
                         const float* __restrict__ Wo,
                         unsigned short* __restrict__ xb, unsigned short* __restrict__ Wqb,
                         unsigned short* __restrict__ Wkb, unsigned short* __restrict__ Wvb,
                         unsigned short* __restrict__ Wob) {
  const int i = blockIdx.x * 256 + threadIdx.x;
  const float* src;
  unsigned short* dst;
  int off;
  if (i < 2097152) {
    src = x; dst = xb; off = i;
  } else {
    const int j = i - 2097152;
    const int wsel = j >> 18;
    off = j & 262143;
    src = wsel == 0 ? Wq : wsel == 1 ? Wk : wsel == 2 ? Wv : Wo;
    dst = wsel == 0 ? Wqb : wsel == 1 ? Wkb : wsel == 2 ? Wvb : Wob;
  }
  float4 v = reinterpret_cast<const float4*>(src)[off];
  ushort4 o;
  o.x = f2bf(v.x); o.y = f2bf(v.y); o.z = f2bf(v.z); o.w = f2bf(v.w);
  reinterpret_cast<ushort4*>(dst)[off] = o;
}

// 128x128-tile GEMM body, K=1024, NT (A[M,1024] x B[N,1024]^T).
// Triple-buffered LDS (lookahead-2 staging), counted vmcnt(4) + raw barrier,
// conflict-free XOR swizzle for 64B rows: s(row) = ((row>>1)&3)<<4.
// oscale multiplies the accumulator in the epilogue (used to fold the
// softmax scale into the Q projection).
template <typename OutT>
static __device__ __forceinline__ void gemm_tile(const unsigned short* __restrict__ A,
                                                 const unsigned short* __restrict__ B,
                                                 OutT* __restrict__ C,
                                                 int brow, int bcol, int ldc,
                                                 short* sA, short* sB, float oscale) {
  const int t = threadIdx.x;
  const int w = t >> 6, l = t & 63, lg = l >> 4, lr = l & 15;
  const int wr = w >> 1, wc = w & 1;

  f32x4 acc[4][4] = {};

  auto stage = [&](int buf, int kt) {
#pragma unroll
    for (int r = 0; r < 2; ++r) {
      const int byteoff = t * 16 + r * 4096;      // 8 KB per matrix-tile
      const int row = byteoff >> 6;               // 64 B per row (32 bf16)
      const int inrow = (byteoff & 63) ^ (((row >> 1) & 3) << 4);  // inv-swz src
      gload_lds16((const char*)A + ((size_t)(brow + row) * 1024 + kt) * 2 + inrow,
                  (char*)(sA + buf * 4096) + byteoff);
      gload_lds16((const char*)B + ((size_t)(bcol + row) * 1024 + kt) * 2 + inrow,
                  (char*)(sB + buf * 4096) + byteoff);
    }
  };

  stage(0, 0);
  stage(1, 32);
  int cur = 0;

  for (int kti = 0; kti < 32; ++kti) {
    if (kti < 31) WAIT4_BARRIER();  // tile kti landed; tile kti+1 stays in flight
    else         WAIT0_BARRIER();
    if (kti + 2 < 32) {
      int b2 = cur + 2; if (b2 >= 3) b2 -= 3;
      stage(b2, (kti + 2) << 5);
    }
    const char* sAc = (const char*)(sA + cur * 4096);
    const char* sBc = (const char*)(sB + cur * 4096);

    short8 af[4], bfr[4];
#pragma unroll
    for (int m = 0; m < 4; ++m) {
      const int arow = wr * 64 + m * 16 + lr;
      af[m] = *reinterpret_cast<const short8*>(
          sAc + arow * 64 + ((lg * 16) ^ (((arow >> 1) & 3) << 4)));
    }
#pragma unroll
    for (int n = 0; n < 4; ++n) {
      const int brw = wc * 64 + n * 16 + lr;
      bfr[n] = *reinterpret_cast<const short8*>(
          sBc + brw * 64 + ((lg * 16) ^ (((brw >> 1) & 3) << 4)));
    }
    __builtin_amdgcn_s_setprio(1);
#pragma unroll
    for (int m = 0; m < 4; ++m)
#pragma unroll
      for (int n = 0; n < 4; ++n)
        acc[m][n] = __builtin_amdgcn_mfma_f32_16x16x32_bf16(af[m], bfr[n], acc[m][n], 0, 0, 0);
    __builtin_amdgcn_s_setprio(0);

    ++cur; if (cur == 3) cur = 0;
  }

  // C/D layout: col = lane&15, row = (lane>>4)*4 + reg  [m89 verified]
#pragma unroll
  for (int m = 0; m < 4; ++m) {
#pragma unroll
    for (int n = 0; n < 4; ++n) {
#pragma unroll
      for (int j = 0; j < 4; ++j) {
        const int rr = brow + wr * 64 + m * 16 + lg * 4 + j;
        const int cc = bcol + wc * 64 + n * 16 + lr;
        if constexpr (sizeof(OutT) == 2) {
          C[(size_t)rr * ldc + cc] = (OutT)f2bf(acc[m][n][j] * oscale);
        } else {
          C[(size_t)rr * ldc + cc] = acc[m][n][j] * oscale;
        }
      }
    }
  }
}

// Fused Q/K/V projections: 1536 blocks, XCD-chunked.
// Q output is pre-scaled by 1/sqrt(dk)*log2(e) (folds softmax scale; QK^T
// then lands directly in the exp2 domain).
__global__ __launch_bounds__(256) void gemm_qkv(const unsigned short* __restrict__ xb,
                                                const unsigned short* __restrict__ Wqb,
                                                const unsigned short* __restrict__ Wkb,
                                                const unsigned short* __restrict__ Wvb,
                                                unsigned short* __restrict__ Qb,
                                                unsigned short* __restrict__ Kb,
                                                unsigned short* __restrict__ Vt) {
  __shared__ short sA[3][4096];
  __shared__ short sB[3][4096];
  const int i = blockIdx.x;
  const int lid = (i & 7) * 192 + (i >> 3);  // bijective: 1536 = 8*192
  const int z = lid >> 9, r = lid & 511;

  const unsigned short *A, *B;
  unsigned short* C;
  int brow, bcol, ldc;
  float oscale = 1.0f;
  if (z == 2) {
    A = Wvb; B = xb; C = Vt;
    brow = (r & 7) << 7; bcol = (r >> 3) << 7; ldc = 8192;
  } else {
    A = xb; B = z ? Wkb : Wqb; C = z ? Kb : Qb;
    brow = (r >> 3) << 7; bcol = (r & 7) << 7; ldc = 1024;
    if (z == 0) oscale = 0.125f * 1.44269504089f;  // 1/sqrt(dk) * log2(e)
  }
  gemm_tile<unsigned short>(A, B, C, brow, bcol, ldc, sA[0], sB[0], oscale);
}

// Final projection: out = AO Wo^T, f32 out. 512 blocks, XCD-chunked.
__global__ __launch_bounds__(256) void gemm_out(const unsigned short* __restrict__ AO,
                                                const unsigned short* __restrict__ Wob,
                                                float* __restrict__ out) {
  __shared__ short sA[3][4096];
  __shared__ short sB[3][4096];
  const int i = blockIdx.x;
  const int lid = (i & 7) * 64 + (i >> 3);  // bijective: 512 = 8*64
  gemm_tile<float>(AO, Wob, out, (lid >> 3) << 7, (lid & 7) << 7, 1024,
                   sA[0], sB[0], 1.0f);
}

// Causal flash attention: swapped-QK^T per-lane softmax, paired q-tiles
// flattened into one 33-tile sequence. DOUBLE-buffered K/V (40 KB LDS ->
// 4 blocks/CU; round-6's 3-buf cost occupancy 4->2 and regressed), stage
// issued at top of iter, drain-all barrier at end (iter compute covers the
// L2 latency). Q pre-scaled (exp2 domain). Defer-max + setprio.
__global__ __launch_bounds__(256) void attn_kernel(const unsigned short* __restrict__ Qg,
                                                   const unsigned short* __restrict__ Kg,
                                                   const unsigned short* __restrict__ Vtg,
                                                   unsigned short* __restrict__ AO) {
  const int S = 2048, D = 1024, SN = 8192;
  const int i = blockIdx.x;
  const int lid = (i & 7) * 128 + (i >> 3);  // XCD k <- lids [128k,128k+128)
  const int qp = lid & 15;
  const int bh = lid >> 4;
  const int b = bh >> 4, h = bh & 15;
  const int t = threadIdx.x;
  const int w = t >> 6, l = t & 63, lg = l >> 4, lr = l & 15;

  __shared__ short sK[2][4096];  // [kv=64][dk=64], XOR-swizzled 128B rows
  __shared__ short sV[2][4096];  // [dk=64][kv=64] (=V^T), XOR-swizzled
  __shared__ short sP[4096];     // per-wave P[q=16][kv=64], XOR-swizzled

  int sboff[2], slin[2], srow[2];
#pragma unroll
  for (int r = 0; r < 2; ++r) {
    sboff[r] = t * 16 + r * 4096;
    srow[r] = sboff[r] >> 7;                            // 128 B per row
    slin[r] = (sboff[r] & 127) ^ ((srow[r] & 7) << 4);  // inverse-swizzled src
  }
  const char* Kbase = (const char*)Kg + ((size_t)(b * S) * D + h * 64) * 2;
  const char* Vbase = (const char*)Vtg + ((size_t)(h * 64) * SN + (size_t)b * S) * 2;

  const int nkv0 = qp + 1;       // half0: qt=qp, tiles 0..qp
  const int qt1 = 31 - qp;       // half1: qt=31-qp, tiles 0..31-qp (33 total)

  auto stage = [&](int buf, int j) {
    const int kvt = (j < nkv0) ? j : j - nkv0;
    const size_t kv0 = (size_t)kvt * 64;
#pragma unroll
    for (int r = 0; r < 2; ++r) {
      gload_lds16(Kbase + (kv0 + srow[r]) * 2048 + slin[r],
                  (char*)sK + buf * 8192 + sboff[r]);
      gload_lds16(Vbase + (size_t)srow[r] * 16384 + kv0 * 2 + slin[r],
                  (char*)sV + buf * 8192 + sboff[r]);
    }
  };
  auto load_qf = [&](int qt, short8* qf) {
    const unsigned short* qbase =
        Qg + (size_t)(b * S + qt * 64 + w * 16 + lr) * D + h * 64;
    qf[0] = *reinterpret_cast<const short8*>(qbase + lg * 8);
    qf[1] = *reinterpret_cast<const short8*>(qbase + 32 + lg * 8);
  };

  short8 qf[2], qfB[2];
  load_qf(qp, qf);       // both halves' Q preloaded at prologue
  load_qf(qt1, qfB);
  stage(0, 0);

  f32x4 o[4] = {};
  float m = -INFINITY, lsum = 0.f;
  int cur = 0;

  auto epilogue = [&](int qt) {
    const float inv = 1.f / lsum;
    unsigned short* orow = AO + (size_t)(b * S + qt * 64 + w * 16 + lr) * D + h * 64;
#pragma unroll
    for (int dn = 0; dn < 4; ++dn) {
      ushort4 ov;
      ov.x = f2bf(o[dn][0] * inv); ov.y = f2bf(o[dn][1] * inv);
      ov.z = f2bf(o[dn][2] * inv); ov.w = f2bf(o[dn][3] * inv);
      *reinterpret_cast<ushort4*>(orow + dn * 16 + lg * 4) = ov;
    }
  };

  WAIT0_BARRIER();  // tile 0 staged

#pragma unroll 1
  for (int j = 0; j < 33; ++j) {
    const bool h1 = (j >= nkv0);
    const int kvt = h1 ? j - nkv0 : j;
    const int qt = h1 ? qt1 : qp;

    if (j + 1 < 33) stage(cur ^ 1, j + 1);  // latency hidden by this iter

    const char* sKc = (const char*)sK + cur * 8192;
    const char* sVc = (const char*)sV + cur * 8192;

    // S^T (exp2-domain, Q pre-scaled): sc[n][r] at lane (lg,lr) =
    //   S[q = w*16+lr][kv = n*16 + lg*4 + r]
    f32x4 sc[4] = {};
    __builtin_amdgcn_s_setprio(1);
#pragma unroll
    for (int n = 0; n < 4; ++n) {
#pragma unroll
      for (int kk = 0; kk < 2; ++kk) {
        const int row = n * 16 + lr;
        const short8 kf = *reinterpret_cast<const short8*>(
            sKc + (row << 7) + ((kk * 64 + lg * 16) ^ ((row & 7) << 4)));
        sc[n] = __builtin_amdgcn_mfma_f32_16x16x32_bf16(kf, qf[kk], sc[n], 0, 0, 0);
      }
    }
    __builtin_amdgcn_s_setprio(0);

    // causal mask (diagonal tile only); no scale mul needed (pre-scaled Q)
    if (kvt == qt) {
      const int ql = w * 16 + lr;
#pragma unroll
      for (int n = 0; n < 4; ++n)
#pragma unroll
        for (int r = 0; r < 4; ++r)
          if ((n * 16 + lg * 4 + r) > ql) sc[n][r] = -INFINITY;
    }

    // per-lane online softmax with defer-max (T13, THR=8 in log2 domain)
    float mx = sc[0][0];
#pragma unroll
    for (int n = 0; n < 4; ++n)
#pragma unroll
      for (int r = 0; r < 4; ++r) mx = fmaxf(mx, sc[n][r]);
    mx = fmaxf(mx, __shfl_xor(mx, 16));
    mx = fmaxf(mx, __shfl_xor(mx, 32));
    if (!__all(mx <= m + 8.0f)) {
      const float mnew = fmaxf(m, mx);
      const float alpha = __builtin_amdgcn_exp2f(m - mnew);
      m = mnew;
      lsum *= alpha;
#pragma unroll
      for (int dn = 0; dn < 4; ++dn) o[dn] *= alpha;
    }

    float p[4][4];
    float s = 0.f;
#pragma unroll
    for (int n = 0; n < 4; ++n) {
#pragma unroll
      for (int r = 0; r < 4; ++r) {
        const float e = __builtin_amdgcn_exp2f(sc[n][r] - m);
        p[n][r] = e;
        s += e;
      }
    }
    s += __shfl_xor(s, 16);
    s += __shfl_xor(s, 32);
    lsum += s;

    // P -> sP (rows = q = lr), wave-private (no barrier; same-wave lgkm order)
#pragma unroll
    for (int n = 0; n < 4; ++n) {
      ushort4 pk;
      pk.x = f2bf(p[n][0]); pk.y = f2bf(p[n][1]);
      pk.z = f2bf(p[n][2]); pk.w = f2bf(p[n][3]);
      *reinterpret_cast<ushort4*>(
          (char*)sP + (w << 11) + (lr << 7) + ((n * 32 + lg * 8) ^ ((lr & 7) << 4))) = pk;
    }

    // O^T += Vt . P^T
    __builtin_amdgcn_s_setprio(1);
#pragma unroll
    for (int kk = 0; kk < 2; ++kk) {
      const short8 pa = *reinterpret_cast<const short8*>(
          (const char*)sP + (w << 11) + (lr << 7) +
          ((kk * 64 + lg * 16) ^ ((lr & 7) << 4)));
#pragma unroll
      for (int dn = 0; dn < 4; ++dn) {
        const int vrow = dn * 16 + lr;
        const short8 vb = *reinterpret_cast<const short8*>(
            sVc + (vrow << 7) + ((kk * 64 + lg * 16) ^ ((vrow & 7) << 4)));
        o[dn] = __builtin_amdgcn_mfma_f32_16x16x32_bf16(vb, pa, o[dn], 0, 0, 0);
      }
    }
    __builtin_amdgcn_s_setprio(0);

    if (j == nkv0 - 1) {  // end of half0: store, reset, switch Q
      epilogue(qp);
#pragma unroll
      for (int dn = 0; dn < 4; ++dn) o[dn] = f32x4{0.f, 0.f, 0.f, 0.f};
      m = -INFINITY; lsum = 0.f;
      qf[0] = qfB[0]; qf[1] = qfB[1];
    }

    if (j + 1 < 33) WAIT0_BARRIER();  // next tile staged; guards buf reuse
    cur ^= 1;
  }
  epilogue(qt1);
}

extern "C" void kernel_launch(void* const* d_in, const int* in_sizes, int n_in,
                              void* d_out, int out_size, void* d_ws, size_t ws_size,
                              hipStream_t stream) {
  const float* x  = (const float*)d_in[0];
  const float* Wq = (const float*)d_in[1];
  const float* Wk = (const float*)d_in[2];
  const float* Wv = (const float*)d_in[3];
  const float* Wo = (const float*)d_in[4];
  float* out = (float*)d_out;

  char* ws = (char*)d_ws;
  unsigned short* xb  = (unsigned short*)(ws);               // 8192x1024 (16 MB)
  unsigned short* Wqb = (unsigned short*)(ws + 16777216);
  unsigned short* Wkb = (unsigned short*)(ws + 18874368);
  unsigned short* Wvb = (unsigned short*)(ws + 20971520);
  unsigned short* Wob = (unsigned short*)(ws + 23068672);
  unsigned short* Qb  = (unsigned short*)(ws + 25165824);    // 8192x1024
  unsigned short* Kb  = (unsigned short*)(ws + 41943040);    // 8192x1024
  unsigned short* Vt  = (unsigned short*)(ws + 58720256);    // 1024x8192 (V^T)
  unsigned short* AO  = (unsigned short*)(ws + 75497472);    // 8192x1024

  cast_all<<<12288, 256, 0, stream>>>(x, Wq, Wk, Wv, Wo, xb, Wqb, Wkb, Wvb, Wob);
  gemm_qkv<<<1536, 256, 0, stream>>>(xb, Wqb, Wkb, Wvb, Qb, Kb, Vt);
  attn_kernel<<<1024, 256, 0, stream>>>(Qb, Kb, Vt, AO);
  gemm_out<<<512, 256, 0, stream>>>(AO, Wob, out);
}